// Round 2
// baseline (503.957 us; speedup 1.0000x reference)
//
#include <hip/hip_runtime.h>

// Activation1d (BigVGAN-style anti-aliased snake-beta), fp32.
// x: (B=16, C=512, T=8192). 2x upsample (K=12) -> snake -> 2x downsample.
//
// Index math (verified in round 1, absmax 1.6e-2 vs 1.2e-1 threshold):
//   up[2s]   = 2*(f1*x(s+2)+f3*x(s+1)+f5*x(s)+f7*x(s-1)+f9*x(s-2)+f11*x(s-3))
//   up[2s+1] = 2*(f0*x(s+3)+f2*x(s+2)+f4*x(s+1)+f6*x(s)+f8*x(s-1)+f10*x(s-2))
//   act[t] = up[t] + exp(-beta)' * sin(up[t]*exp(alpha))^2
//   out[n] = sum_k df[k] * act[clamp(2n+k-5, 0, 2T-1)]
//
// Round-2 changes:
//  * W=16 outputs/thread (was 8): act duplication 26/16 -> 42/32 (-24% VALU/out)
//  * Branch-free main kernel: load base clamped to [0, T-32]; the 2 edge
//    threads/row produce garbage which a tiny fixup kernel overwrites.
//    (Round 1: ~12% of waves executed BOTH the interior and the 182-load
//    clamped edge path.)

#define T_LEN 8192
#define C_CH  512
#define B_N   16
#define W     16
#define BLOCK 256

__global__ __launch_bounds__(BLOCK) void act1d_main(
    const float* __restrict__ x,
    const float* __restrict__ uf_g,
    const float* __restrict__ df_g,
    const float* __restrict__ alpha,
    const float* __restrict__ beta,
    float* __restrict__ out)
{
    const int T = T_LEN;
    const int bid = blockIdx.x;
    const int row = bid >> 1;              // 2 chunks per row: 2*256*16 = 8192
    const int chunk = bid & 1;
    const int c = row & (C_CH - 1);
    const int nb = chunk * (BLOCK * W) + (int)threadIdx.x * W;
    const long rowoff = (long)row * T;
    const float* xrow = x + rowoff;

    // filters: uniform -> s_load into SGPRs. Fold UP_RATIO=2 gain into uf.
    float uf[12], df[12];
#pragma unroll
    for (int k = 0; k < 12; ++k) { uf[k] = 2.0f * uf_g[k]; df[k] = df_g[k]; }

    const float ea   = __expf(alpha[c]);
    const float invb = 1.0f / (__expf(beta[c]) + 1e-9f);

    // x window: x[nb-8 .. nb+24). Edge threads clamp the BASE only (their
    // outputs are garbage; fixup kernel overwrites n in [0,16) u [T-16,T)).
    const int base = min(max(nb - 8, 0), T - 32);
    float xr[32];
    const float4* xv = (const float4*)(xrow + base);
#pragma unroll
    for (int k = 0; k < 8; ++k) {
        float4 v = xv[k];
        xr[4*k+0] = v.x; xr[4*k+1] = v.y; xr[4*k+2] = v.z; xr[4*k+3] = v.w;
    }

    // act values at t = 2*nb-5+j, j in [0,42)
    float a[42];
#pragma unroll
    for (int j = 0; j < 42; ++j) {
        // s = t>>1 = nb + ((j-5)>>1); xr[xi] == x[s], xi = ((j-5)>>1)+8
        const int xi = ((j - 5) >> 1) + 8;
        float up;
        if ((j & 1) == 0) {   // t odd
            up = uf[0]*xr[xi+3] + uf[2]*xr[xi+2] + uf[4]*xr[xi+1]
               + uf[6]*xr[xi]   + uf[8]*xr[xi-1] + uf[10]*xr[xi-2];
        } else {              // t even
            up = uf[1]*xr[xi+2] + uf[3]*xr[xi+1] + uf[5]*xr[xi]
               + uf[7]*xr[xi-1] + uf[9]*xr[xi-2] + uf[11]*xr[xi-3];
        }
        const float sv = __sinf(up * ea);
        a[j] = fmaf(invb * sv, sv, up);
    }

    // down-conv: out[nb+d] = sum_k df[k] * a[2d+k]
    float4* ov = (float4*)(out + rowoff + nb);
#pragma unroll
    for (int q = 0; q < 4; ++q) {
        float o[4];
#pragma unroll
        for (int dd = 0; dd < 4; ++dd) {
            const int d = 4*q + dd;
            float acc = 0.0f;
#pragma unroll
            for (int k = 0; k < 12; ++k) acc = fmaf(df[k], a[2*d + k], acc);
            o[dd] = acc;
        }
        ov[q] = make_float4(o[0], o[1], o[2], o[3]);
    }
}

// Fixup: recompute the 32 edge outputs of each row (n in [0,16) u [T-16,T))
// with fully clamped gathers. Runs after act1d_main on the same stream.
__global__ __launch_bounds__(64) void act1d_edge(
    const float* __restrict__ x,
    const float* __restrict__ uf_g,
    const float* __restrict__ df_g,
    const float* __restrict__ alpha,
    const float* __restrict__ beta,
    float* __restrict__ out)
{
    const int T = T_LEN;
    const int row = blockIdx.x;
    const int i = (int)threadIdx.x;
    if (i >= 32) return;
    const int n = (i < 16) ? i : (T - 32 + i);
    const int c = row & (C_CH - 1);
    const long rowoff = (long)row * T;
    const float* xrow = x + rowoff;

    float uf[12], df[12];
#pragma unroll
    for (int k = 0; k < 12; ++k) { uf[k] = 2.0f * uf_g[k]; df[k] = df_g[k]; }
    const float ea   = __expf(alpha[c]);
    const float invb = 1.0f / (__expf(beta[c]) + 1e-9f);

    float acc = 0.0f;
#pragma unroll
    for (int k = 0; k < 12; ++k) {
        int t = 2*n + k - 5;
        t = min(max(t, 0), 2*T - 1);
        const int s = t >> 1;
        const int par = t & 1;
        float xv7[7];
#pragma unroll
        for (int m = 0; m < 7; ++m) {
            int g = s - 3 + m;
            g = min(max(g, 0), T - 1);
            xv7[m] = xrow[g];
        }
        const float upo = uf[0]*xv7[6] + uf[2]*xv7[5] + uf[4]*xv7[4]
                        + uf[6]*xv7[3] + uf[8]*xv7[2] + uf[10]*xv7[1];
        const float upe = uf[1]*xv7[5] + uf[3]*xv7[4] + uf[5]*xv7[3]
                        + uf[7]*xv7[2] + uf[9]*xv7[1] + uf[11]*xv7[0];
        const float up = par ? upo : upe;
        const float sv = __sinf(up * ea);
        const float av = fmaf(invb * sv, sv, up);
        acc = fmaf(df[k], av, acc);
    }
    out[rowoff + n] = acc;
}

extern "C" void kernel_launch(void* const* d_in, const int* in_sizes, int n_in,
                              void* d_out, int out_size, void* d_ws, size_t ws_size,
                              hipStream_t stream) {
    const float* x  = (const float*)d_in[0];
    const float* uf = (const float*)d_in[1];
    const float* df = (const float*)d_in[2];
    const float* al = (const float*)d_in[3];
    const float* be = (const float*)d_in[4];
    float* outp = (float*)d_out;

    const int rows = B_N * C_CH;                       // 8192
    const int grid = rows * (T_LEN / (BLOCK * W));     // 16384
    act1d_main<<<grid, BLOCK, 0, stream>>>(x, uf, df, al, be, outp);
    act1d_edge<<<rows, 64, 0, stream>>>(x, uf, df, al, be, outp);
}